// Round 3
// baseline (525.288 us; speedup 1.0000x reference)
//
#include <hip/hip_runtime.h>
#include <math.h>

// Problem constants (fixed by reference): B=2, L=256, H=512, NH=8, DH=64
// Strategy: B_D[b,n,q,k] = sum_h rpe[b,q,k,h] * Wtil[b,q,n,h] with
//   Wtil[b,q,n,h] = sum_d (q+v_bias)[b,q,n,d] * Wr[n*64+d, h]   (avoids the
//   131072x512x512 rel projection entirely -> kernel is HBM-bound on rpe).
// A_C via kproj directly (K=64 contraction), bk folded into kproj, br folded
// into per-(b,q,n) constant (softmax-invariant but computed for exactness).

// ---------------- workspace layout (floats) ----------------
// WqT      @ 0        (262144)
// WkT      @ 262144
// WvT      @ 524288
// WfT      @ 786432
// qproj    @ 1048576
// kproj    @ 1310720
// vproj    @ 1572864
// wtil     @ 1835008  (2*256*8*512 = 2097152)
// consts   @ 3932160  (2*256*8 = 4096)
// attn_out @ 3936256  (262144)
// total 4198400 floats = 16.8 MB

static constexpr size_t OFF_WQT = 0;
static constexpr size_t OFF_WKT = 262144;
static constexpr size_t OFF_WVT = 524288;
static constexpr size_t OFF_WFT = 786432;
static constexpr size_t OFF_QP  = 1048576;
static constexpr size_t OFF_KP  = 1310720;
static constexpr size_t OFF_VP  = 1572864;
static constexpr size_t OFF_WT  = 1835008;
static constexpr size_t OFF_CST = 3932160;
static constexpr size_t OFF_AO  = 3936256;

// 16-lane prefix reduce via DPP row_shr (VALU pipe, no LDS traffic).
// After this, lane 15 of each 16-lane row holds the sum of its row.
__device__ __forceinline__ float red16(float p) {
  p += __int_as_float(__builtin_amdgcn_update_dpp(0, __float_as_int(p), 0x111, 0xf, 0xf, true));
  p += __int_as_float(__builtin_amdgcn_update_dpp(0, __float_as_int(p), 0x112, 0xf, 0xf, true));
  p += __int_as_float(__builtin_amdgcn_update_dpp(0, __float_as_int(p), 0x114, 0xf, 0xf, true));
  p += __int_as_float(__builtin_amdgcn_update_dpp(0, __float_as_int(p), 0x118, 0xf, 0xf, true));
  return p;
}

// ---------------- K0: transpose the 4 weight matrices (512x512) ----------------
__global__ __launch_bounds__(256) void transpose_k(
    const float* __restrict__ s0, const float* __restrict__ s1,
    const float* __restrict__ s2, const float* __restrict__ s3,
    float* __restrict__ d0, float* __restrict__ d1,
    float* __restrict__ d2, float* __restrict__ d3)
{
  __shared__ __align__(16) float tl[32][36];
  int z = blockIdx.z;
  const float* src = (z == 0) ? s0 : (z == 1) ? s1 : (z == 2) ? s2 : s3;
  float* dst       = (z == 0) ? d0 : (z == 1) ? d1 : (z == 2) ? d2 : d3;
  int t = threadIdx.x;
  int r  = t >> 3;         // 0..31
  int cc = (t & 7) << 2;   // 0,4,..,28
  int k0 = blockIdx.x * 32;
  int c0 = blockIdx.y * 32;
  // tl[r][cc+j] = src[c0+r][k0+cc+j]
  float4 v = *(const float4*)(src + (size_t)(c0 + r) * 512 + k0 + cc);
  *(float4*)&tl[r][cc] = v;
  __syncthreads();
  // dst[k0+r][c0+cc+j] = src[c0+cc+j][k0+r] = tl[cc+j][r]
  float4 o;
  o.x = tl[cc + 0][r]; o.y = tl[cc + 1][r]; o.z = tl[cc + 2][r]; o.w = tl[cc + 3][r];
  *(float4*)(dst + (size_t)(k0 + r) * 512 + c0 + cc) = o;
}

// ---------------- row-wave GEMM: OUT[m,c] = sum_k A[m,k]*WT[k,c] + bias[c] ----------------
// M=512, N=512, K=512. Block: 256 thr, 8 rows x half the columns, K split over 4 waves.
__device__ __forceinline__ void rwgemm_body(
    const float* __restrict__ A, const float* __restrict__ WT,
    const float* __restrict__ bias, float* __restrict__ OUT)
{
  __shared__ __align__(16) float A_lds[8 * 512];
  __shared__ __align__(16) float part[4][8][256];
  int t = threadIdx.x;
  int w = t >> 6, lane = t & 63;
  int rg = blockIdx.x, ch = blockIdx.y;
  #pragma unroll
  for (int e = t * 4; e < 4096; e += 1024)
    *(float4*)&A_lds[e] = *(const float4*)(A + (size_t)rg * 4096 + e);
  __syncthreads();
  float4 acc[8];
  #pragma unroll
  for (int r = 0; r < 8; ++r) acc[r] = make_float4(0.f, 0.f, 0.f, 0.f);
  const float* wp = WT + (size_t)(w * 128) * 512 + ch * 256 + lane * 4;
  #pragma unroll 2
  for (int kk = 0; kk < 128; ++kk) {
    float4 w4 = *(const float4*)wp; wp += 512;
    int k = w * 128 + kk;
    #pragma unroll
    for (int r = 0; r < 8; ++r) {
      float a = A_lds[r * 512 + k];  // wave-uniform broadcast
      acc[r].x = fmaf(a, w4.x, acc[r].x);
      acc[r].y = fmaf(a, w4.y, acc[r].y);
      acc[r].z = fmaf(a, w4.z, acc[r].z);
      acc[r].w = fmaf(a, w4.w, acc[r].w);
    }
  }
  #pragma unroll
  for (int r = 0; r < 8; ++r)
    *(float4*)&part[w][r][lane * 4] = acc[r];
  __syncthreads();
  // reduce 4 wave-partials; first 256 threads (t==c_local)
  if (t < 256) {
    #pragma unroll
    for (int r = 0; r < 8; ++r) {
      float s = part[0][r][t] + part[1][r][t] + part[2][r][t] + part[3][r][t]
              + bias[ch * 256 + t];
      OUT[(size_t)(rg * 8 + r) * 512 + ch * 256 + t] = s;
    }
  }
}

__global__ __launch_bounds__(256) void proj3_k(
    const float* __restrict__ query, const float* __restrict__ key, const float* __restrict__ value,
    const float* __restrict__ WqT, const float* __restrict__ WkT, const float* __restrict__ WvT,
    const float* __restrict__ bq, const float* __restrict__ bk, const float* __restrict__ bv,
    float* __restrict__ qp, float* __restrict__ kp, float* __restrict__ vp)
{
  int z = blockIdx.z;
  const float* A    = (z == 0) ? query : (z == 1) ? key : value;
  const float* WT   = (z == 0) ? WqT   : (z == 1) ? WkT : WvT;
  const float* bias = (z == 0) ? bq    : (z == 1) ? bk  : bv;
  float* OUT        = (z == 0) ? qp    : (z == 1) ? kp  : vp;
  rwgemm_body(A, WT, bias, OUT);
}

__global__ __launch_bounds__(256) void gemm_rw_k(
    const float* __restrict__ A, const float* __restrict__ WT,
    const float* __restrict__ bias, float* __restrict__ OUT)
{
  rwgemm_body(A, WT, bias, OUT);
}

// ---------------- K2: Wtil[b,q,n,h] = sum_d (qproj+v_bias)[b,q,n*64+d] * Wr[n*64+d, h]
//                 + consts[b,q,n] = sum_d (qproj+v_bias)[..d] * br[n*64+d]
// grid (qq=64, nq=2, b=2), block 256 (4 waves, wave w -> head n = nq*4+w), 4 q rows per block.
__global__ __launch_bounds__(256) void wtilde_k(
    const float* __restrict__ qproj, const float* __restrict__ Wr,
    const float* __restrict__ v_bias, const float* __restrict__ br,
    float* __restrict__ wtil, float* __restrict__ consts)
{
  __shared__ __align__(16) float qv[4 * 512];
  int qq = blockIdx.x, nq = blockIdx.y, b = blockIdx.z;
  int t = threadIdx.x;
  #pragma unroll
  for (int j = 0; j < 8; ++j) {
    int e = t + j * 256;
    int i = e >> 9, h = e & 511;
    qv[e] = qproj[(size_t)(b * 256 + qq * 4 + i) * 512 + h] + v_bias[h];
  }
  __syncthreads();
  int w = t >> 6, lane = t & 63, l4 = lane * 4;
  int n = nq * 4 + w;
  float4 accA[4], accB[4];
  #pragma unroll
  for (int i = 0; i < 4; ++i) { accA[i] = make_float4(0,0,0,0); accB[i] = make_float4(0,0,0,0); }
  const float* wr = Wr + (size_t)n * 64 * 512;
  for (int d = 0; d < 64; ++d) {
    float4 wa = *(const float4*)(wr + (size_t)d * 512 + l4);
    float4 wb = *(const float4*)(wr + (size_t)d * 512 + 256 + l4);
    #pragma unroll
    for (int i = 0; i < 4; ++i) {
      float s = qv[i * 512 + n * 64 + d];
      accA[i].x = fmaf(s, wa.x, accA[i].x);
      accA[i].y = fmaf(s, wa.y, accA[i].y);
      accA[i].z = fmaf(s, wa.z, accA[i].z);
      accA[i].w = fmaf(s, wa.w, accA[i].w);
      accB[i].x = fmaf(s, wb.x, accB[i].x);
      accB[i].y = fmaf(s, wb.y, accB[i].y);
      accB[i].z = fmaf(s, wb.z, accB[i].z);
      accB[i].w = fmaf(s, wb.w, accB[i].w);
    }
  }
  #pragma unroll
  for (int i = 0; i < 4; ++i) {
    float* wo = wtil + (size_t)((b * 256 + qq * 4 + i) * 8 + n) * 512;
    *(float4*)(wo + l4) = accA[i];
    *(float4*)(wo + 256 + l4) = accB[i];
  }
  #pragma unroll
  for (int i = 0; i < 4; ++i) {
    float x = qv[i * 512 + n * 64 + lane] * br[n * 64 + lane];
    #pragma unroll
    for (int off = 32; off; off >>= 1) x += __shfl_xor(x, off);
    if (lane == 0) consts[(size_t)(b * 256 + qq * 4 + i) * 8 + n] = x;
  }
}

// ---------------- K3: fused attention per (b,q). Block 512 thr (8 waves). ----------------
// Wave w handles score rows kpos = r*8+w. Wtil fragments live in registers
// (lane owns h in {4*lane..4*lane+3} U {256+4*lane..}); DPP 16-lane reduce.
__global__ __launch_bounds__(512, 4) void attn_k(
    const float* __restrict__ qproj, const float* __restrict__ kproj,
    const float* __restrict__ vproj, const float* __restrict__ rpe,
    const float* __restrict__ u_bias, const float* __restrict__ wtil,
    const float* __restrict__ consts, const int* __restrict__ seq_len,
    const int* __restrict__ lex_num, float* __restrict__ attn_out)
{
  __shared__ __align__(16) float part[256][36];  // [kpos][sub*8+n], stride 36 for banks/align
  __shared__ __align__(16) float sc[8][260];     // scores then attn, [n][kpos]
  int q = blockIdx.x, b = blockIdx.y;
  int bq = b * 256 + q;
  int t = threadIdx.x, w = t >> 6, lane = t & 63;
  int sub = lane >> 4;
  bool wlast = (lane & 15) == 15;
  int l4 = lane * 4;

  // ---- A_C: sc[n][kpos] = sum_d (q+u)[n,d] * kproj[b,kpos,n*64+d] (bk inside kproj) ----
  {
    float4 qa = *(const float4*)(qproj + (size_t)bq * 512 + l4);
    float4 ua = *(const float4*)(u_bias + l4);
    float4 qb = *(const float4*)(qproj + (size_t)bq * 512 + 256 + l4);
    float4 ub = *(const float4*)(u_bias + 256 + l4);
    qa.x += ua.x; qa.y += ua.y; qa.z += ua.z; qa.w += ua.w;
    qb.x += ub.x; qb.y += ub.y; qb.z += ub.z; qb.w += ub.w;
    for (int r = 0; r < 32; ++r) {
      int kpos = r * 8 + w;
      const float* kr = kproj + (size_t)(b * 256 + kpos) * 512;
      float4 ka = *(const float4*)(kr + l4);
      float4 kb = *(const float4*)(kr + 256 + l4);
      float p1 = ka.x * qa.x + ka.y * qa.y + ka.z * qa.z + ka.w * qa.w;
      float p2 = kb.x * qb.x + kb.y * qb.y + kb.z * qb.z + kb.w * qb.w;
      p1 = red16(p1);  // lane 15+16s: sum over h in [64s,64s+64) -> head n=s
      p2 = red16(p2);  // -> head n=4+s
      if (wlast) { sc[sub][kpos] = p1; sc[4 + sub][kpos] = p2; }
    }
  }

  // ---- B_D: part[kpos][sub*8+n] = 16-lane partial of sum_h rpe[..,h]*Wtil[n,h] ----
  {
    float4 wt0[8], wt1[8];
    #pragma unroll
    for (int n = 0; n < 8; ++n) {
      const float* wtp = wtil + (size_t)(bq * 8 + n) * 512;
      wt0[n] = *(const float4*)(wtp + l4);
      wt1[n] = *(const float4*)(wtp + 256 + l4);
    }
    const float* rp = rpe + (size_t)bq * 256 * 512;
    for (int r = 0; r < 32; ++r) {
      int kpos = r * 8 + w;
      const float* rr = rp + (size_t)kpos * 512;
      float4 ra = *(const float4*)(rr + l4);
      float4 rb = *(const float4*)(rr + 256 + l4);
      float p[8];
      #pragma unroll
      for (int n = 0; n < 8; ++n) {
        float s = ra.x * wt0[n].x;
        s = fmaf(ra.y, wt0[n].y, s);
        s = fmaf(ra.z, wt0[n].z, s);
        s = fmaf(ra.w, wt0[n].w, s);
        s = fmaf(rb.x, wt1[n].x, s);
        s = fmaf(rb.y, wt1[n].y, s);
        s = fmaf(rb.z, wt1[n].z, s);
        s = fmaf(rb.w, wt1[n].w, s);
        p[n] = s;
      }
      #pragma unroll
      for (int n = 0; n < 8; ++n) p[n] = red16(p[n]);
      if (wlast) {
        *(float4*)&part[kpos][sub * 8]     = make_float4(p[0], p[1], p[2], p[3]);
        *(float4*)&part[kpos][sub * 8 + 4] = make_float4(p[4], p[5], p[6], p[7]);
      }
    }
  }
  __syncthreads();

  // ---- combine + scale + mask ----
  {
    int total = seq_len[b] + lex_num[b];
    int kpos = t & 255;
    int nb = t >> 8;
    #pragma unroll
    for (int i = 0; i < 4; ++i) {
      int n = nb + i * 2;
      float s = sc[n][kpos]
              + part[kpos][n] + part[kpos][8 + n] + part[kpos][16 + n] + part[kpos][24 + n]
              + consts[(size_t)bq * 8 + n];
      s *= 0.125f;  // 1/sqrt(64)
      sc[n][kpos] = (kpos < total) ? s : -1e30f;
    }
  }
  __syncthreads();

  // ---- softmax per head (wave w = head n) ----
  {
    int n = w;
    float4 s4 = *(const float4*)&sc[n][l4];
    float m = fmaxf(fmaxf(s4.x, s4.y), fmaxf(s4.z, s4.w));
    #pragma unroll
    for (int off = 32; off; off >>= 1) m = fmaxf(m, __shfl_xor(m, off));
    float e0 = __expf(s4.x - m), e1 = __expf(s4.y - m);
    float e2 = __expf(s4.z - m), e3 = __expf(s4.w - m);
    float ss = e0 + e1 + e2 + e3;
    #pragma unroll
    for (int off = 32; off; off >>= 1) ss += __shfl_xor(ss, off);
    float inv = 1.0f / ss;
    *(float4*)&sc[n][l4] = make_float4(e0 * inv, e1 * inv, e2 * inv, e3 * inv);
  }
  __syncthreads();

  // ---- PV: attn_out[b,q,n*64+d] = sum_k attn[n,k]*vproj[b,k,n*64+d] ----
  {
    int n = w, d = lane;
    const float* vp = vproj + (size_t)b * 256 * 512 + n * 64 + d;
    float a0 = 0.f, a1 = 0.f, a2 = 0.f, a3 = 0.f;
    for (int k0 = 0; k0 < 256; k0 += 4) {
      a0 = fmaf(sc[n][k0 + 0], vp[(size_t)(k0 + 0) * 512], a0);
      a1 = fmaf(sc[n][k0 + 1], vp[(size_t)(k0 + 1) * 512], a1);
      a2 = fmaf(sc[n][k0 + 2], vp[(size_t)(k0 + 2) * 512], a2);
      a3 = fmaf(sc[n][k0 + 3], vp[(size_t)(k0 + 3) * 512], a3);
    }
    attn_out[(size_t)bq * 512 + n * 64 + d] = a0 + a1 + a2 + a3;
  }
}

// ---------------- host launch ----------------
extern "C" void kernel_launch(void* const* d_in, const int* in_sizes, int n_in,
                              void* d_out, int out_size, void* d_ws, size_t ws_size,
                              hipStream_t stream) {
  const float* key    = (const float*)d_in[0];
  const float* query  = (const float*)d_in[1];
  const float* value  = (const float*)d_in[2];
  const float* rpe    = (const float*)d_in[3];
  const float* Wk     = (const float*)d_in[4];
  const float* bk     = (const float*)d_in[5];
  const float* Wq     = (const float*)d_in[6];
  const float* bq     = (const float*)d_in[7];
  const float* Wv     = (const float*)d_in[8];
  const float* bv     = (const float*)d_in[9];
  const float* Wr     = (const float*)d_in[10];
  const float* br     = (const float*)d_in[11];
  const float* u_bias = (const float*)d_in[12];
  const float* v_bias = (const float*)d_in[13];
  const float* Wf     = (const float*)d_in[14];
  const float* bf     = (const float*)d_in[15];
  const int* seq_len  = (const int*)d_in[16];
  const int* lex_num  = (const int*)d_in[17];
  float* out = (float*)d_out;
  float* ws = (float*)d_ws;

  float* WqT    = ws + OFF_WQT;
  float* WkT    = ws + OFF_WKT;
  float* WvT    = ws + OFF_WVT;
  float* WfT    = ws + OFF_WFT;
  float* qp     = ws + OFF_QP;
  float* kp     = ws + OFF_KP;
  float* vp     = ws + OFF_VP;
  float* wtil   = ws + OFF_WT;
  float* consts = ws + OFF_CST;
  float* ao     = ws + OFF_AO;

  transpose_k<<<dim3(16, 16, 4), 256, 0, stream>>>(Wq, Wk, Wv, Wf, WqT, WkT, WvT, WfT);
  proj3_k<<<dim3(64, 2, 3), 256, 0, stream>>>(query, key, value, WqT, WkT, WvT,
                                              bq, bk, bv, qp, kp, vp);
  wtilde_k<<<dim3(64, 2, 2), 256, 0, stream>>>(qp, Wr, v_bias, br, wtil, consts);
  attn_k<<<dim3(256, 2), 512, 0, stream>>>(qp, kp, vp, rpe, u_bias, wtil, consts,
                                           seq_len, lex_num, ao);
  gemm_rw_k<<<dim3(64, 2, 1), 256, 0, stream>>>(ao, WfT, bf, out);
}

// Round 4
// 522.160 us; speedup vs baseline: 1.0060x; 1.0060x over previous
//
#include <hip/hip_runtime.h>
#include <math.h>

// Problem constants (fixed by reference): B=2, L=256, H=512, NH=8, DH=64
// Strategy: B_D[b,n,q,k] = sum_h rpe[b,q,k,h] * Wtil[b,q,n,h] with
//   Wtil[b,q,n,h] = sum_d (q+v_bias)[b,q,n,d] * Wr[n*64+d, h]   (avoids the
//   131072x512x512 rel projection entirely -> kernel is HBM-bound on rpe).
// A_C via kproj directly (K=64 contraction), bk folded into kproj, br folded
// into per-(b,q,n) constant (softmax-invariant but computed for exactness).
//
// Round-4 change: attn_k launch_bounds (512,4)->(512,2) and two-pass B_D
// (h in [0,256) then [256,512)) to cut peak live VGPRs ~100 -> ~60 and
// remove any chance of in-loop scratch spills (H1 for the 525us measurement).

// ---------------- workspace layout (floats) ----------------
static constexpr size_t OFF_WQT = 0;
static constexpr size_t OFF_WKT = 262144;
static constexpr size_t OFF_WVT = 524288;
static constexpr size_t OFF_WFT = 786432;
static constexpr size_t OFF_QP  = 1048576;
static constexpr size_t OFF_KP  = 1310720;
static constexpr size_t OFF_VP  = 1572864;
static constexpr size_t OFF_WT  = 1835008;
static constexpr size_t OFF_CST = 3932160;
static constexpr size_t OFF_AO  = 3936256;

// 16-lane prefix reduce via DPP row_shr (VALU pipe, no LDS traffic).
// After this, lane 15 of each 16-lane row holds the sum of its row.
__device__ __forceinline__ float red16(float p) {
  p += __int_as_float(__builtin_amdgcn_update_dpp(0, __float_as_int(p), 0x111, 0xf, 0xf, true));
  p += __int_as_float(__builtin_amdgcn_update_dpp(0, __float_as_int(p), 0x112, 0xf, 0xf, true));
  p += __int_as_float(__builtin_amdgcn_update_dpp(0, __float_as_int(p), 0x114, 0xf, 0xf, true));
  p += __int_as_float(__builtin_amdgcn_update_dpp(0, __float_as_int(p), 0x118, 0xf, 0xf, true));
  return p;
}

// ---------------- K0: transpose the 4 weight matrices (512x512) ----------------
__global__ __launch_bounds__(256) void transpose_k(
    const float* __restrict__ s0, const float* __restrict__ s1,
    const float* __restrict__ s2, const float* __restrict__ s3,
    float* __restrict__ d0, float* __restrict__ d1,
    float* __restrict__ d2, float* __restrict__ d3)
{
  __shared__ __align__(16) float tl[32][36];
  int z = blockIdx.z;
  const float* src = (z == 0) ? s0 : (z == 1) ? s1 : (z == 2) ? s2 : s3;
  float* dst       = (z == 0) ? d0 : (z == 1) ? d1 : (z == 2) ? d2 : d3;
  int t = threadIdx.x;
  int r  = t >> 3;         // 0..31
  int cc = (t & 7) << 2;   // 0,4,..,28
  int k0 = blockIdx.x * 32;
  int c0 = blockIdx.y * 32;
  float4 v = *(const float4*)(src + (size_t)(c0 + r) * 512 + k0 + cc);
  *(float4*)&tl[r][cc] = v;
  __syncthreads();
  float4 o;
  o.x = tl[cc + 0][r]; o.y = tl[cc + 1][r]; o.z = tl[cc + 2][r]; o.w = tl[cc + 3][r];
  *(float4*)(dst + (size_t)(k0 + r) * 512 + c0 + cc) = o;
}

// ---------------- row-wave GEMM: OUT[m,c] = sum_k A[m,k]*WT[k,c] + bias[c] ----------------
__device__ __forceinline__ void rwgemm_body(
    const float* __restrict__ A, const float* __restrict__ WT,
    const float* __restrict__ bias, float* __restrict__ OUT)
{
  __shared__ __align__(16) float A_lds[8 * 512];
  __shared__ __align__(16) float part[4][8][256];
  int t = threadIdx.x;
  int w = t >> 6, lane = t & 63;
  int rg = blockIdx.x, ch = blockIdx.y;
  #pragma unroll
  for (int e = t * 4; e < 4096; e += 1024)
    *(float4*)&A_lds[e] = *(const float4*)(A + (size_t)rg * 4096 + e);
  __syncthreads();
  float4 acc[8];
  #pragma unroll
  for (int r = 0; r < 8; ++r) acc[r] = make_float4(0.f, 0.f, 0.f, 0.f);
  const float* wp = WT + (size_t)(w * 128) * 512 + ch * 256 + lane * 4;
  #pragma unroll 2
  for (int kk = 0; kk < 128; ++kk) {
    float4 w4 = *(const float4*)wp; wp += 512;
    int k = w * 128 + kk;
    #pragma unroll
    for (int r = 0; r < 8; ++r) {
      float a = A_lds[r * 512 + k];  // wave-uniform broadcast
      acc[r].x = fmaf(a, w4.x, acc[r].x);
      acc[r].y = fmaf(a, w4.y, acc[r].y);
      acc[r].z = fmaf(a, w4.z, acc[r].z);
      acc[r].w = fmaf(a, w4.w, acc[r].w);
    }
  }
  #pragma unroll
  for (int r = 0; r < 8; ++r)
    *(float4*)&part[w][r][lane * 4] = acc[r];
  __syncthreads();
  if (t < 256) {
    #pragma unroll
    for (int r = 0; r < 8; ++r) {
      float s = part[0][r][t] + part[1][r][t] + part[2][r][t] + part[3][r][t]
              + bias[ch * 256 + t];
      OUT[(size_t)(rg * 8 + r) * 512 + ch * 256 + t] = s;
    }
  }
}

__global__ __launch_bounds__(256) void proj3_k(
    const float* __restrict__ query, const float* __restrict__ key, const float* __restrict__ value,
    const float* __restrict__ WqT, const float* __restrict__ WkT, const float* __restrict__ WvT,
    const float* __restrict__ bq, const float* __restrict__ bk, const float* __restrict__ bv,
    float* __restrict__ qp, float* __restrict__ kp, float* __restrict__ vp)
{
  int z = blockIdx.z;
  const float* A    = (z == 0) ? query : (z == 1) ? key : value;
  const float* WT   = (z == 0) ? WqT   : (z == 1) ? WkT : WvT;
  const float* bias = (z == 0) ? bq    : (z == 1) ? bk  : bv;
  float* OUT        = (z == 0) ? qp    : (z == 1) ? kp  : vp;
  rwgemm_body(A, WT, bias, OUT);
}

__global__ __launch_bounds__(256) void gemm_rw_k(
    const float* __restrict__ A, const float* __restrict__ WT,
    const float* __restrict__ bias, float* __restrict__ OUT)
{
  rwgemm_body(A, WT, bias, OUT);
}

// ---------------- K2: Wtil + br consts ----------------
__global__ __launch_bounds__(256) void wtilde_k(
    const float* __restrict__ qproj, const float* __restrict__ Wr,
    const float* __restrict__ v_bias, const float* __restrict__ br,
    float* __restrict__ wtil, float* __restrict__ consts)
{
  __shared__ __align__(16) float qv[4 * 512];
  int qq = blockIdx.x, nq = blockIdx.y, b = blockIdx.z;
  int t = threadIdx.x;
  #pragma unroll
  for (int j = 0; j < 8; ++j) {
    int e = t + j * 256;
    int i = e >> 9, h = e & 511;
    qv[e] = qproj[(size_t)(b * 256 + qq * 4 + i) * 512 + h] + v_bias[h];
  }
  __syncthreads();
  int w = t >> 6, lane = t & 63, l4 = lane * 4;
  int n = nq * 4 + w;
  float4 accA[4], accB[4];
  #pragma unroll
  for (int i = 0; i < 4; ++i) { accA[i] = make_float4(0,0,0,0); accB[i] = make_float4(0,0,0,0); }
  const float* wr = Wr + (size_t)n * 64 * 512;
  for (int d = 0; d < 64; ++d) {
    float4 wa = *(const float4*)(wr + (size_t)d * 512 + l4);
    float4 wb = *(const float4*)(wr + (size_t)d * 512 + 256 + l4);
    #pragma unroll
    for (int i = 0; i < 4; ++i) {
      float s = qv[i * 512 + n * 64 + d];
      accA[i].x = fmaf(s, wa.x, accA[i].x);
      accA[i].y = fmaf(s, wa.y, accA[i].y);
      accA[i].z = fmaf(s, wa.z, accA[i].z);
      accA[i].w = fmaf(s, wa.w, accA[i].w);
      accB[i].x = fmaf(s, wb.x, accB[i].x);
      accB[i].y = fmaf(s, wb.y, accB[i].y);
      accB[i].z = fmaf(s, wb.z, accB[i].z);
      accB[i].w = fmaf(s, wb.w, accB[i].w);
    }
  }
  #pragma unroll
  for (int i = 0; i < 4; ++i) {
    float* wo = wtil + (size_t)((b * 256 + qq * 4 + i) * 8 + n) * 512;
    *(float4*)(wo + l4) = accA[i];
    *(float4*)(wo + 256 + l4) = accB[i];
  }
  #pragma unroll
  for (int i = 0; i < 4; ++i) {
    float x = qv[i * 512 + n * 64 + lane] * br[n * 64 + lane];
    #pragma unroll
    for (int off = 32; off; off >>= 1) x += __shfl_xor(x, off);
    if (lane == 0) consts[(size_t)(b * 256 + qq * 4 + i) * 8 + n] = x;
  }
}

// ---------------- K3: fused attention per (b,q). Block 512 thr (8 waves). ----------------
// launch_bounds (512,2): VGPR cap 256 (no forced spill); LDS 45KB still allows
// 3 blocks/CU; actual VGPR use (~60 in hot loop after 2-pass split) keeps 4 waves/SIMD.
__global__ __launch_bounds__(512, 2) void attn_k(
    const float* __restrict__ qproj, const float* __restrict__ kproj,
    const float* __restrict__ vproj, const float* __restrict__ rpe,
    const float* __restrict__ u_bias, const float* __restrict__ wtil,
    const float* __restrict__ consts, const int* __restrict__ seq_len,
    const int* __restrict__ lex_num, float* __restrict__ attn_out)
{
  __shared__ __align__(16) float part[256][36];  // [kpos][sub*8+n]
  __shared__ __align__(16) float sc[8][260];     // scores then attn, [n][kpos]
  int q = blockIdx.x, b = blockIdx.y;
  int bq = b * 256 + q;
  int t = threadIdx.x, w = t >> 6, lane = t & 63;
  int sub = lane >> 4;
  bool wlast = (lane & 15) == 15;
  int l4 = lane * 4;

  // ---- A_C: sc[n][kpos] = sum_d (q+u)[n,d] * kproj[b,kpos,n*64+d] ----
  {
    float4 qa = *(const float4*)(qproj + (size_t)bq * 512 + l4);
    float4 ua = *(const float4*)(u_bias + l4);
    float4 qb = *(const float4*)(qproj + (size_t)bq * 512 + 256 + l4);
    float4 ub = *(const float4*)(u_bias + 256 + l4);
    qa.x += ua.x; qa.y += ua.y; qa.z += ua.z; qa.w += ua.w;
    qb.x += ub.x; qb.y += ub.y; qb.z += ub.z; qb.w += ub.w;
    for (int r = 0; r < 32; ++r) {
      int kpos = r * 8 + w;
      const float* kr = kproj + (size_t)(b * 256 + kpos) * 512;
      float4 ka = *(const float4*)(kr + l4);
      float4 kb = *(const float4*)(kr + 256 + l4);
      float p1 = ka.x * qa.x + ka.y * qa.y + ka.z * qa.z + ka.w * qa.w;
      float p2 = kb.x * qb.x + kb.y * qb.y + kb.z * qb.z + kb.w * qb.w;
      p1 = red16(p1);
      p2 = red16(p2);
      if (wlast) { sc[sub][kpos] = p1; sc[4 + sub][kpos] = p2; }
    }
  }

  // ---- B_D (two passes over h-halves to halve live VGPRs):
  //      part[kpos][sub*8+n] = 16-lane partial of sum_h rpe[..,h]*Wtil[n,h] ----
  {
    const float* rp = rpe + (size_t)bq * 256 * 512;
    #pragma unroll
    for (int pass = 0; pass < 2; ++pass) {
      int hh = pass * 256;
      float4 wt[8];
      #pragma unroll
      for (int n = 0; n < 8; ++n)
        wt[n] = *(const float4*)(wtil + (size_t)(bq * 8 + n) * 512 + hh + l4);
      for (int r = 0; r < 32; ++r) {
        int kpos = r * 8 + w;
        float4 ra = *(const float4*)(rp + (size_t)kpos * 512 + hh + l4);
        float p[8];
        #pragma unroll
        for (int n = 0; n < 8; ++n) {
          float s = ra.x * wt[n].x;
          s = fmaf(ra.y, wt[n].y, s);
          s = fmaf(ra.z, wt[n].z, s);
          s = fmaf(ra.w, wt[n].w, s);
          p[n] = s;
        }
        #pragma unroll
        for (int n = 0; n < 8; ++n) p[n] = red16(p[n]);
        if (wlast) {
          if (pass == 0) {
            *(float4*)&part[kpos][sub * 8]     = make_float4(p[0], p[1], p[2], p[3]);
            *(float4*)&part[kpos][sub * 8 + 4] = make_float4(p[4], p[5], p[6], p[7]);
          } else {
            #pragma unroll
            for (int n = 0; n < 8; ++n) part[kpos][sub * 8 + n] += p[n];
          }
        }
      }
    }
  }
  __syncthreads();

  // ---- combine + scale + mask ----
  {
    int total = seq_len[b] + lex_num[b];
    int kpos = t & 255;
    int nb = t >> 8;
    #pragma unroll
    for (int i = 0; i < 4; ++i) {
      int n = nb + i * 2;
      float s = sc[n][kpos]
              + part[kpos][n] + part[kpos][8 + n] + part[kpos][16 + n] + part[kpos][24 + n]
              + consts[(size_t)bq * 8 + n];
      s *= 0.125f;  // 1/sqrt(64)
      sc[n][kpos] = (kpos < total) ? s : -1e30f;
    }
  }
  __syncthreads();

  // ---- softmax per head (wave w = head n) ----
  {
    int n = w;
    float4 s4 = *(const float4*)&sc[n][l4];
    float m = fmaxf(fmaxf(s4.x, s4.y), fmaxf(s4.z, s4.w));
    #pragma unroll
    for (int off = 32; off; off >>= 1) m = fmaxf(m, __shfl_xor(m, off));
    float e0 = __expf(s4.x - m), e1 = __expf(s4.y - m);
    float e2 = __expf(s4.z - m), e3 = __expf(s4.w - m);
    float ss = e0 + e1 + e2 + e3;
    #pragma unroll
    for (int off = 32; off; off >>= 1) ss += __shfl_xor(ss, off);
    float inv = 1.0f / ss;
    *(float4*)&sc[n][l4] = make_float4(e0 * inv, e1 * inv, e2 * inv, e3 * inv);
  }
  __syncthreads();

  // ---- PV: attn_out[b,q,n*64+d] = sum_k attn[n,k]*vproj[b,k,n*64+d] ----
  {
    int n = w, d = lane;
    const float* vp = vproj + (size_t)b * 256 * 512 + n * 64 + d;
    float a0 = 0.f, a1 = 0.f, a2 = 0.f, a3 = 0.f;
    for (int k0 = 0; k0 < 256; k0 += 4) {
      a0 = fmaf(sc[n][k0 + 0], vp[(size_t)(k0 + 0) * 512], a0);
      a1 = fmaf(sc[n][k0 + 1], vp[(size_t)(k0 + 1) * 512], a1);
      a2 = fmaf(sc[n][k0 + 2], vp[(size_t)(k0 + 2) * 512], a2);
      a3 = fmaf(sc[n][k0 + 3], vp[(size_t)(k0 + 3) * 512], a3);
    }
    attn_out[(size_t)bq * 512 + n * 64 + d] = a0 + a1 + a2 + a3;
  }
}

// ---------------- host launch ----------------
extern "C" void kernel_launch(void* const* d_in, const int* in_sizes, int n_in,
                              void* d_out, int out_size, void* d_ws, size_t ws_size,
                              hipStream_t stream) {
  const float* key    = (const float*)d_in[0];
  const float* query  = (const float*)d_in[1];
  const float* value  = (const float*)d_in[2];
  const float* rpe    = (const float*)d_in[3];
  const float* Wk     = (const float*)d_in[4];
  const float* bk     = (const float*)d_in[5];
  const float* Wq     = (const float*)d_in[6];
  const float* bq     = (const float*)d_in[7];
  const float* Wv     = (const float*)d_in[8];
  const float* bv     = (const float*)d_in[9];
  const float* Wr     = (const float*)d_in[10];
  const float* br     = (const float*)d_in[11];
  const float* u_bias = (const float*)d_in[12];
  const float* v_bias = (const float*)d_in[13];
  const float* Wf     = (const float*)d_in[14];
  const float* bf     = (const float*)d_in[15];
  const int* seq_len  = (const int*)d_in[16];
  const int* lex_num  = (const int*)d_in[17];
  float* out = (float*)d_out;
  float* ws = (float*)d_ws;

  float* WqT    = ws + OFF_WQT;
  float* WkT    = ws + OFF_WKT;
  float* WvT    = ws + OFF_WVT;
  float* WfT    = ws + OFF_WFT;
  float* qp     = ws + OFF_QP;
  float* kp     = ws + OFF_KP;
  float* vp     = ws + OFF_VP;
  float* wtil   = ws + OFF_WT;
  float* consts = ws + OFF_CST;
  float* ao     = ws + OFF_AO;

  transpose_k<<<dim3(16, 16, 4), 256, 0, stream>>>(Wq, Wk, Wv, Wf, WqT, WkT, WvT, WfT);
  proj3_k<<<dim3(64, 2, 3), 256, 0, stream>>>(query, key, value, WqT, WkT, WvT,
                                              bq, bk, bv, qp, kp, vp);
  wtilde_k<<<dim3(64, 2, 2), 256, 0, stream>>>(qp, Wr, v_bias, br, wtil, consts);
  attn_k<<<dim3(256, 2), 512, 0, stream>>>(qp, kp, vp, rpe, u_bias, wtil, consts,
                                           seq_len, lex_num, ao);
  gemm_rw_k<<<dim3(64, 2, 1), 256, 0, stream>>>(ao, WfT, bf, out);
}